// Round 4
// baseline (1513.581 us; speedup 1.0000x reference)
//
#include <hip/hip_runtime.h>

// GRU B=256,T=2000,I=23,H=128 (gate order r,z,n) + mean over T.
// 1 batch row per block, 256 blocks (1/CU). v5: 1024 threads = 16 waves,
// 4 waves/SIMD (was 8 waves / 2 per SIMD).
//
// v5 vs v4:
//  - OCCUPANCY: 16 waves/CU. r3 showed VALUBusy 67% with ~500 stall
//    cycles/step (post-barrier LDS latency + fold/exp dependency chains)
//    that 2 waves/SIMD cannot hide. Per-wave work halves (wave owns 8
//    h-rows: 4 r/z + 2 n gate-slots per lane), weights/lane halve so
//    <=128 VGPR fits 4 waves/SIMD.
//  - CHEAPER FOLDS: slot perms re-derived so slot-folds sit on DPP levels:
//    fold16x4 = 10 instr (was 15), n-gate folds = 2x fold16x2 of 8 instr
//    (was 2x15). Lane mapping: r/z slot u = kt&3 (bit0=j-offset,
//    bit1=gate), n slot = kt&1 (same j-offset bit) -> epilogue stays
//    in-register, z fetched from lane kt^2 via one quad_perm DPP.
//  - x prefetch via incremental 32-bit element offset (no per-step mul).

#define Bb 256
#define Tt 2000
#define Ii 23
#define Hh 128

typedef float v2f __attribute__((ext_vector_type(2)));
typedef float v4f __attribute__((ext_vector_type(4)));

template <int N> struct ic { static constexpr int v = N; };

template <int ctrl>
__device__ __forceinline__ float dpp_movf(float v) {
    int r = __builtin_amdgcn_update_dpp(0, __builtin_bit_cast(int, v),
                                        ctrl, 0xf, 0xf, true);
    return __builtin_bit_cast(float, r);
}
__device__ __forceinline__ float swz_xor4(float v) {
    int r = __builtin_amdgcn_ds_swizzle(__builtin_bit_cast(int, v), 0x101F);
    return __builtin_bit_cast(float, r);
}
__device__ __forceinline__ void pk_fma(v2f& a, v2f b, v2f c) {
    asm("v_pk_fma_f32 %0, %1, %2, %0" : "+v"(a) : "v"(b), "v"(c));
}
__device__ __forceinline__ v2f pk_mul(v2f b, v2f c) {
    v2f d;
    asm("v_pk_mul_f32 %0, %1, %2" : "=v"(d) : "v"(b), "v"(c));
    return d;
}

// Fold 4 acc slots over the 16 kt-lanes. Slot u = i ^ (kt&3):
// slot-bit0 folds at xor1 (DPP quad_perm), slot-bit1 at xor2 (DPP
// quad_perm); xor4 (DS swizzle) and xor8 (row_ror:8) are self-folds.
// Lane ends with the full k-sum of slot u = kt&3.  10 instructions.
__device__ __forceinline__ float fold16x4(const float a[4]) {
    float b0 = a[0] + dpp_movf<0xB1>(a[1]);
    float b1 = a[2] + dpp_movf<0xB1>(a[3]);
    float c  = b0 + dpp_movf<0x4E>(b1);
    c += swz_xor4(c);
    return c + dpp_movf<0x128>(c);
}
// Fold 2 acc slots: slot-bit0 at xor1; xor2/xor4/xor8 self-folds.
// Lane ends with full k-sum of slot u = kt&1.  8 instructions.
__device__ __forceinline__ float fold16x2(float a0, float a1) {
    float b = a0 + dpp_movf<0xB1>(a1);
    b += dpp_movf<0x4E>(b);
    b += swz_xor4(b);
    return b + dpp_movf<0x128>(b);
}

__global__ __launch_bounds__(1024, 4)
void gru_fused(const float* __restrict__ x,     // [B,T,I]
               const float* __restrict__ W_ih,  // [3H,I]
               const float* __restrict__ W_hh,  // [3H,H]
               const float* __restrict__ b_ih,  // [3H]
               const float* __restrict__ b_hh,  // [3H]
               float* __restrict__ out)         // [B,H]
{
    const int b   = blockIdx.x;
    const int tid = threadIdx.x;
    const int wid = tid >> 6;           // 0..15
    const int l   = tid & 63;
    const int kt  = l & 15;             // k in [kt*8, kt*8+8)
    const int kb  = kt * 8;
    const int p2  = kt & 3;             // r/z slot perm (bit0=joff, bit1=gate)
    const int pv  = kt & 1;             // n slot perm (joff)
    const int jbase = wid * 8 + ((l >> 4) << 1);   // gr-group owns 2 j's

    __shared__ __align__(16) float h_db[2][16][12];  // double-buffered h

    // ---- r/z recurrent weights: slot i <-> gate u = i^p2 ----
    v2f wrz2[4][4];
    #pragma unroll
    for (int i = 0; i < 4; ++i) {
        const int u = i ^ p2;
        const int g = (u >> 1) * Hh + jbase + (u & 1);
        const v2f* wp = reinterpret_cast<const v2f*>(W_hh + (size_t)g * Hh + kb);
        #pragma unroll
        for (int kk = 0; kk < 4; ++kk) wrz2[i][kk] = wp[kk];
    }
    // ---- n recurrent weights: slot iv <-> row jbase + (iv^pv) ----
    v2f wn2[2][4];
    #pragma unroll
    for (int iv = 0; iv < 2; ++iv) {
        const int g = 2 * Hh + jbase + (iv ^ pv);
        const v2f* wp = reinterpret_cast<const v2f*>(W_hh + (size_t)g * Hh + kb);
        #pragma unroll
        for (int kk = 0; kk < 4; ++kk) wn2[iv][kk] = wp[kk];
    }

    // ---- x-side weights: lane kt covers x idx xi0 (+1 if kt<7) ----
    const int xi0   = (kt < 7) ? kt * 2 : 7 + kt;   // 0..13 / 14..22
    const int xoffd = (kt < 7) ? 1 : 0;
    v2f wx2[4];
    #pragma unroll
    for (int i = 0; i < 4; ++i) {
        const int u = i ^ p2;
        const int g = (u >> 1) * Hh + jbase + (u & 1);
        wx2[i][0] = W_ih[(size_t)g * Ii + xi0];
        wx2[i][1] = xoffd ? W_ih[(size_t)g * Ii + xi0 + 1] : 0.0f;
    }
    v2f wxn2[2];
    #pragma unroll
    for (int iv = 0; iv < 2; ++iv) {
        const int g = 2 * Hh + jbase + (iv ^ pv);
        wxn2[iv][0] = W_ih[(size_t)g * Ii + xi0];
        wxn2[iv][1] = xoffd ? W_ih[(size_t)g * Ii + xi0 + 1] : 0.0f;
    }

    // ---- per-lane biases (post-fold) ----
    const int gp = (p2 >> 1) * Hh + jbase + (p2 & 1);
    const float brz_l = b_ih[gp] + b_hh[gp];
    const int jn = jbase + pv;
    const float bhn_l = b_hh[2 * Hh + jn];
    const float bxn_l = b_ih[2 * Hh + jn];

    const float* xrow = x + (size_t)b * Tt * Ii;

    // ---- init ----
    if (tid < Hh) h_db[0][tid >> 3][tid & 7] = 0.0f;
    int xo = xi0;                       // incremental x element offset
    float xa = xrow[xo];
    float xb = xrow[xo + xoffd];
    xo += Ii;
    float h_reg = 0.0f, acc_mean = 0.0f;
    const bool writer = ((kt & 14) == 0);   // kt in {0,1}: r-lane, unique joff
    const int  jw = jbase + pv;
    __syncthreads();

    auto body = [&](auto CUR, int s) {
        constexpr int cur = decltype(CUR)::v;
        const int step = s + cur;

        // ---- x prefetch for step+1 (L1-hot 92B row) ----
        const float na = xrow[xo];
        const float nb = xrow[xo + xoffd];
        xo += (step + 2 < Tt) ? Ii : 0;

        // ---- h tile: 8 floats as 2x b128 ----
        const v4f hA = *reinterpret_cast<const v4f*>(&h_db[cur][kt][0]);
        const v4f hB = *reinterpret_cast<const v4f*>(&h_db[cur][kt][4]);
        v2f hp[4];
        hp[0] = __builtin_shufflevector(hA, hA, 0, 1);
        hp[1] = __builtin_shufflevector(hA, hA, 2, 3);
        hp[2] = __builtin_shufflevector(hB, hB, 0, 1);
        hp[3] = __builtin_shufflevector(hB, hB, 2, 3);

        // ---- packed recurrent MACs: 4 r/z + 2 n slots ----
        v2f acc[4], accn[2];
        #pragma unroll
        for (int i = 0; i < 4; ++i) acc[i] = pk_mul(wrz2[i][0], hp[0]);
        #pragma unroll
        for (int iv = 0; iv < 2; ++iv) accn[iv] = pk_mul(wn2[iv][0], hp[0]);
        #pragma unroll
        for (int kk = 1; kk < 4; ++kk) {
            #pragma unroll
            for (int i = 0; i < 4; ++i) pk_fma(acc[i], wrz2[i][kk], hp[kk]);
            #pragma unroll
            for (int iv = 0; iv < 2; ++iv) pk_fma(accn[iv], wn2[iv][kk], hp[kk]);
        }

        // ---- x-side: r/z into acc pre-fold; n x-side separate ----
        v2f xpv; xpv[0] = xa; xpv[1] = xb;
        #pragma unroll
        for (int i = 0; i < 4; ++i) pk_fma(acc[i], wx2[i], xpv);
        float arz[4];
        #pragma unroll
        for (int i = 0; i < 4; ++i) arz[i] = acc[i][0] + acc[i][1];
        float an0 = accn[0][0] + accn[0][1];
        float an1 = accn[1][0] + accn[1][1];
        v2f tx0 = pk_mul(wxn2[0], xpv);
        v2f tx1 = pk_mul(wxn2[1], xpv);
        float ax0 = tx0[0] + tx0[1];
        float ax1 = tx1[0] + tx1[1];

        // ---- in-wave folds + biases ----
        const float rz_tot = fold16x4(arz) + brz_l;   // slot kt&3
        const float ghn = fold16x2(an0, an1) + bhn_l; // slot kt&1
        const float gxn = fold16x2(ax0, ax1) + bxn_l; // slot kt&1

        // rotate x prefetch
        xa = na; xb = nb;

        // ---- in-register epilogue (valid where gate-bit kt1==0) ----
        const float zin = dpp_movf<0x4E>(rz_tot);     // partner gate, same j
        const float r  = __builtin_amdgcn_rcpf(1.0f + __expf(-rz_tot));
        const float z  = __builtin_amdgcn_rcpf(1.0f + __expf(-zin));
        const float npre = fmaf(r, ghn, gxn);
        const float tt2  = __builtin_amdgcn_rcpf(1.0f + __expf(-2.0f * npre));
        const float nn   = fmaf(2.0f, tt2, -1.0f);    // tanh(npre)
        const float h_new = fmaf(z, h_reg - nn, nn);
        h_reg = h_new;
        if (writer) {
            acc_mean += h_new;
            h_db[cur ^ 1][jw >> 3][jw & 7] = h_new;
        }
        __syncthreads();   // the ONLY barrier per step
    };

    for (int s = 0; s < Tt; s += 2) {
        body(ic<0>{}, s);
        body(ic<1>{}, s);
    }

    if (writer) out[(size_t)b * Hh + jw] = acc_mean * (1.0f / Tt);
}

extern "C" void kernel_launch(void* const* d_in, const int* in_sizes, int n_in,
                              void* d_out, int out_size, void* d_ws, size_t ws_size,
                              hipStream_t stream) {
    const float* x    = (const float*)d_in[0];
    const float* W_ih = (const float*)d_in[1];
    const float* W_hh = (const float*)d_in[2];
    const float* b_ih = (const float*)d_in[3];
    const float* b_hh = (const float*)d_in[4];
    float* out = (float*)d_out;

    gru_fused<<<Bb, 1024, 0, stream>>>(x, W_ih, W_hh, b_ih, b_hh, out);
}

// Round 5
// 1275.065 us; speedup vs baseline: 1.1871x; 1.1871x over previous
//
#include <hip/hip_runtime.h>

// GRU B=256,T=2000,I=23,H=128 (gate order r,z,n) + mean over T.
// 1 batch row per block, 256 blocks (1/CU). 512 threads = 8 waves, 2/SIMD.
//
// v6 vs v4 (v5's 16-wave experiment regressed and is reverted):
//  - BARRIER DRAIN FIX: __syncthreads() lowers to s_waitcnt vmcnt(0)
//    lgkmcnt(0) + s_barrier, draining the per-step x prefetch loads and
//    putting their L2/HBM miss latency on every step's critical path.
//    Replaced with inline-asm {s_waitcnt lgkmcnt(0); s_barrier}: LDS (h)
//    ordering is preserved; lane-private read-only x loads stay in flight
//    across the barrier.
//  - DEPTH-2 x prefetch with parity-owned register pairs (even steps use
//    P0, odd use P1; a body reloads its own pair for step+2). The vmcnt
//    wait therefore lands ~2 steps (~1300 cy) after issue.
//  - exp2 PRESCALE: r/z weights+biases scaled by log2e, n-side by 2*log2e
//    at load; sigmoid/tanh use raw v_exp_f32 (no input muls).

#define Bb 256
#define Tt 2000
#define Ii 23
#define Hh 128

typedef float v2f __attribute__((ext_vector_type(2)));
typedef float v4f __attribute__((ext_vector_type(4)));

template <int N> struct ic { static constexpr int v = N; };

template <int ctrl>
__device__ __forceinline__ float dpp_movf(float v) {
    int r = __builtin_amdgcn_update_dpp(0, __builtin_bit_cast(int, v),
                                        ctrl, 0xf, 0xf, true);
    return __builtin_bit_cast(float, r);
}
__device__ __forceinline__ float swz_xor4(float v) {
    int r = __builtin_amdgcn_ds_swizzle(__builtin_bit_cast(int, v), 0x101F);
    return __builtin_bit_cast(float, r);
}
__device__ __forceinline__ void pk_fma(v2f& a, v2f b, v2f c) {
    asm("v_pk_fma_f32 %0, %1, %2, %0" : "+v"(a) : "v"(b), "v"(c));
}
__device__ __forceinline__ v2f pk_mul(v2f b, v2f c) {
    v2f d;
    asm("v_pk_mul_f32 %0, %1, %2" : "=v"(d) : "v"(b), "v"(c));
    return d;
}
__device__ __forceinline__ float fexp2(float x) {
#if __has_builtin(__builtin_amdgcn_exp2f)
    return __builtin_amdgcn_exp2f(x);
#else
    return exp2f(x);
#endif
}
// LDS-only barrier: does NOT drain vmcnt (x prefetch stays in flight).
__device__ __forceinline__ void bar_lds() {
    asm volatile("s_waitcnt lgkmcnt(0)\n\ts_barrier" ::: "memory");
}

// fold 8 accs over 16 kt-lanes, XOR-permuted: lane ends with the full sum
// of virtual slot p(kt) = ((kt&1)<<2)|(kt&2)|((kt>>2)&1).
__device__ __forceinline__ float fold16x8(const float a[8]) {
    float b0 = a[0] + dpp_movf<0xB1>(a[4]);   // xor1 (quad_perm [1,0,3,2])
    float b1 = a[1] + dpp_movf<0xB1>(a[5]);
    float b2 = a[2] + dpp_movf<0xB1>(a[6]);
    float b3 = a[3] + dpp_movf<0xB1>(a[7]);
    float c0 = b0 + dpp_movf<0x4E>(b2);       // xor2 (quad_perm [2,3,0,1])
    float c1 = b1 + dpp_movf<0x4E>(b3);
    float d  = c0 + swz_xor4(c1);             // xor4 (only DS hop)
    return d + dpp_movf<0x128>(d);            // xor8 (row_ror:8)
}
// fold 4 accs over 16 kt-lanes: lane ends with full sum of slot
// p2(kt) = (kt&2)|((kt>>2)&1).
__device__ __forceinline__ float fold16x4(const float a[4]) {
    float b0 = a[0] + dpp_movf<0xB1>(a[0]);
    float b1 = a[1] + dpp_movf<0xB1>(a[1]);
    float b2 = a[2] + dpp_movf<0xB1>(a[2]);
    float b3 = a[3] + dpp_movf<0xB1>(a[3]);
    float c0 = b0 + dpp_movf<0x4E>(b2);
    float c1 = b1 + dpp_movf<0x4E>(b3);
    float d  = c0 + swz_xor4(c1);
    return d + dpp_movf<0x128>(d);
}

__global__ __launch_bounds__(512, 2)
void gru_fused(const float* __restrict__ x,     // [B,T,I]
               const float* __restrict__ W_ih,  // [3H,I]
               const float* __restrict__ W_hh,  // [3H,H]
               const float* __restrict__ b_ih,  // [3H]
               const float* __restrict__ b_hh,  // [3H]
               float* __restrict__ out)         // [B,H]
{
    const int b   = blockIdx.x;
    const int tid = threadIdx.x;
    const int wid = tid >> 6;
    const int l   = tid & 63;
    const int kt  = l & 15;
    const int kb  = kt * 8;
    const int p   = ((kt & 1) << 2) | (kt & 2) | ((kt >> 2) & 1);
    const int p2  = (kt & 2) | ((kt >> 2) & 1);
    const int jbase = wid * 16 + ((l >> 4) << 2);

    __shared__ __align__(16) float h_db[2][16][12];  // double-buffered h

    const float L2E = 1.4426950408889634f;   // log2(e)
    const float K2  = 2.0f * L2E;

    // ---- recurrent weights as k-pairs (v2f); r/z prescaled by log2e,
    //      n prescaled by 2*log2e ----
    v2f wrz2[8][4];
    #pragma unroll
    for (int i = 0; i < 8; ++i) {
        const int u = i ^ p;
        const int g = (u >> 2) * Hh + jbase + (u & 3);
        const v2f* wp = reinterpret_cast<const v2f*>(W_hh + (size_t)g * Hh + kb);
        #pragma unroll
        for (int kk = 0; kk < 4; ++kk) {
            v2f w = wp[kk];
            w[0] *= L2E; w[1] *= L2E;
            wrz2[i][kk] = w;
        }
    }
    v2f wn2[4][4];
    #pragma unroll
    for (int q = 0; q < 4; ++q) {
        const int g = 2 * Hh + jbase + (q ^ p2);
        const v2f* wp = reinterpret_cast<const v2f*>(W_hh + (size_t)g * Hh + kb);
        #pragma unroll
        for (int kk = 0; kk < 4; ++kk) {
            v2f w = wp[kk];
            w[0] *= K2; w[1] *= K2;
            wn2[q][kk] = w;
        }
    }

    // ---- x-side weights: lane kt covers x idx xi0 (+1 if kt<7) ----
    const int xi0  = (kt < 7) ? kt * 2 : 7 + kt;      // 0..13 / 14..22
    const int xoff = (kt < 7) ? 1 : 0;                // dup-load if 0 (w=0)
    v2f wx2[8];
    #pragma unroll
    for (int i = 0; i < 8; ++i) {
        const int u = i ^ p;
        const int g = (u >> 2) * Hh + jbase + (u & 3);
        wx2[i][0] = W_ih[(size_t)g * Ii + xi0] * L2E;
        wx2[i][1] = xoff ? W_ih[(size_t)g * Ii + xi0 + 1] * L2E : 0.0f;
    }
    v2f wxn2[4];
    #pragma unroll
    for (int q = 0; q < 4; ++q) {
        const int g = 2 * Hh + jbase + (q ^ p2);
        wxn2[q][0] = W_ih[(size_t)g * Ii + xi0] * K2;
        wxn2[q][1] = xoff ? W_ih[(size_t)g * Ii + xi0 + 1] * K2 : 0.0f;
    }

    // ---- per-lane biases (post-fold), prescaled ----
    const int gp = (p >> 2) * Hh + jbase + (p & 3);
    const float brz_l = (b_ih[gp] + b_hh[gp]) * L2E;
    const int jn = jbase + p2;
    const float bhn_l = b_hh[2 * Hh + jn] * K2;
    const float bxn_l = b_ih[2 * Hh + jn] * K2;

    const float* xrow = x + (size_t)b * Tt * Ii;

    // ---- init ----
    if (tid < Hh) h_db[0][tid >> 3][tid & 7] = 0.0f;
    // depth-2 x prefetch: P0 serves even steps, P1 odd steps.
    float x0a = xrow[xi0],      x0b = xrow[xi0 + xoff];
    float x1a = xrow[Ii + xi0], x1b = xrow[Ii + xi0 + xoff];
    int xob = 2 * Ii + xi0;                 // element index of row step+2
    float h_reg = 0.0f, acc_mean = 0.0f;
    const bool writer = ((kt & 9) == 0);    // kt in {0,2,4,6} -> p in {0,2,1,3}
    const int  jw = jbase + p;
    bar_lds();

    auto body = [&](auto CUR, int s) {
        constexpr int cur = decltype(CUR)::v;
        const int step = s + cur;

        // ---- h tile: 8 floats as 2x b128, split into pairs ----
        const v4f hA = *reinterpret_cast<const v4f*>(&h_db[cur][kt][0]);
        const v4f hB = *reinterpret_cast<const v4f*>(&h_db[cur][kt][4]);
        v2f hp[4];
        hp[0] = __builtin_shufflevector(hA, hA, 0, 1);
        hp[1] = __builtin_shufflevector(hA, hA, 2, 3);
        hp[2] = __builtin_shufflevector(hB, hB, 0, 1);
        hp[3] = __builtin_shufflevector(hB, hB, 2, 3);

        // ---- packed recurrent MACs: 8 r/z + 4 n gates ----
        v2f acc[8], accn[4];
        #pragma unroll
        for (int i = 0; i < 8; ++i) acc[i] = pk_mul(wrz2[i][0], hp[0]);
        #pragma unroll
        for (int q = 0; q < 4; ++q) accn[q] = pk_mul(wn2[q][0], hp[0]);
        #pragma unroll
        for (int kk = 1; kk < 4; ++kk) {
            #pragma unroll
            for (int i = 0; i < 8; ++i) pk_fma(acc[i], wrz2[i][kk], hp[kk]);
            #pragma unroll
            for (int q = 0; q < 4; ++q) pk_fma(accn[q], wn2[q][kk], hp[kk]);
        }

        // ---- x-side: r/z folds into acc; n kept separate ----
        v2f xpv;
        if constexpr (cur == 0) { xpv[0] = x0a; xpv[1] = x0b; }
        else                    { xpv[0] = x1a; xpv[1] = x1b; }
        #pragma unroll
        for (int i = 0; i < 8; ++i) pk_fma(acc[i], wx2[i], xpv);
        float arz[8];
        #pragma unroll
        for (int i = 0; i < 8; ++i) arz[i] = acc[i][0] + acc[i][1];
        float an[4], axn[4];
        #pragma unroll
        for (int q = 0; q < 4; ++q) {
            an[q] = accn[q][0] + accn[q][1];
            v2f tq = pk_mul(wxn2[q], xpv);
            axn[q] = tq[0] + tq[1];
        }

        // ---- reload this parity's x pair for step+2 (vmcnt wait lands
        //      ~2 steps downstream; barrier no longer drains it) ----
        if constexpr (cur == 0) { x0a = xrow[xob]; x0b = xrow[xob + xoff]; }
        else                    { x1a = xrow[xob]; x1b = xrow[xob + xoff]; }
        if (step + 3 < Tt) xob += Ii;

        // ---- folds (all in-wave) + biases ----
        const float rz_tot = fold16x8(arz) + brz_l;   // r/z pre-act at slot p
        const float ghn = fold16x4(an) + bhn_l;       // rec n-sum at slot p2
        const float gxn = fold16x4(axn) + bxn_l;      // x-side n-sum at slot p2

        // ---- in-register epilogue (valid on even-kt lanes) ----
        const float zin = dpp_movf<0xB1>(rz_tot);     // neighbor's z pre-act
        const float r  = __builtin_amdgcn_rcpf(1.0f + fexp2(-rz_tot));
        const float z  = __builtin_amdgcn_rcpf(1.0f + fexp2(-zin));
        const float npre = fmaf(r, ghn, gxn);         // pre-scaled by 2log2e
        const float tt2  = __builtin_amdgcn_rcpf(1.0f + fexp2(-npre));
        const float nn   = fmaf(2.0f, tt2, -1.0f);    // tanh
        const float h_new = fmaf(z, h_reg - nn, nn);
        h_reg = h_new;
        if (writer) {
            acc_mean += h_new;
            h_db[cur ^ 1][jw >> 3][jw & 7] = h_new;
        }
        bar_lds();   // LDS-only barrier, once per step
    };

    for (int s = 0; s < Tt; s += 2) {
        body(ic<0>{}, s);
        body(ic<1>{}, s);
    }

    if (writer) out[(size_t)b * Hh + jw] = acc_mean * (1.0f / Tt);
}

extern "C" void kernel_launch(void* const* d_in, const int* in_sizes, int n_in,
                              void* d_out, int out_size, void* d_ws, size_t ws_size,
                              hipStream_t stream) {
    const float* x    = (const float*)d_in[0];
    const float* W_ih = (const float*)d_in[1];
    const float* W_hh = (const float*)d_in[2];
    const float* b_ih = (const float*)d_in[3];
    const float* b_hh = (const float*)d_in[4];
    float* out = (float*)d_out;

    gru_fused<<<Bb, 512, 0, stream>>>(x, W_ih, W_hh, b_ih, b_hh, out);
}

// Round 6
// 1273.529 us; speedup vs baseline: 1.1885x; 1.0012x over previous
//
#include <hip/hip_runtime.h>

// GRU B=256,T=2000,I=23,H=128 (gate order r,z,n) + mean over T.
// 1 batch row per block, 256 blocks (1/CU). 512 threads = 8 waves, 2/SIMD.
//
// v8 vs v6: WEIGHT REGISTER PINNING.
// r5 counters: VGPR_Count=88 but persistent weight state is ~120 floats,
// WRITE_SIZE flat (no scratch spill) and FETCH_SIZE=24 GB (~47 KB per
// block-step) -> LLVM rematerialized the invariant weight loads INSIDE the
// step loop, re-fetching W_hh/W_ih slices every timestep (VMEM issue +
// addressing + vmcnt stalls on the critical path). Fix: pass every
// persistent weight/bias through an opaque empty inline-asm "+v" after
// loading; the value is no longer provably an invariant load, so it must
// stay allocated in VGPRs (~180 VGPR, still 2 waves/SIMD).
// Everything else identical to v6 (LDS-only barrier, depth-2 x prefetch,
// exp2 prescale, packed v_pk_fma_f32 MACs).

#define Bb 256
#define Tt 2000
#define Ii 23
#define Hh 128

typedef float v2f __attribute__((ext_vector_type(2)));
typedef float v4f __attribute__((ext_vector_type(4)));

template <int N> struct ic { static constexpr int v = N; };

template <int ctrl>
__device__ __forceinline__ float dpp_movf(float v) {
    int r = __builtin_amdgcn_update_dpp(0, __builtin_bit_cast(int, v),
                                        ctrl, 0xf, 0xf, true);
    return __builtin_bit_cast(float, r);
}
__device__ __forceinline__ float swz_xor4(float v) {
    int r = __builtin_amdgcn_ds_swizzle(__builtin_bit_cast(int, v), 0x101F);
    return __builtin_bit_cast(float, r);
}
__device__ __forceinline__ void pk_fma(v2f& a, v2f b, v2f c) {
    asm("v_pk_fma_f32 %0, %1, %2, %0" : "+v"(a) : "v"(b), "v"(c));
}
__device__ __forceinline__ v2f pk_mul(v2f b, v2f c) {
    v2f d;
    asm("v_pk_mul_f32 %0, %1, %2" : "=v"(d) : "v"(b), "v"(c));
    return d;
}
__device__ __forceinline__ float fexp2(float x) {
#if __has_builtin(__builtin_amdgcn_exp2f)
    return __builtin_amdgcn_exp2f(x);
#else
    return exp2f(x);
#endif
}
// Opaque register pin: kills load-rematerialization, forces VGPR residency.
__device__ __forceinline__ void pin(v2f& v) { asm("" : "+v"(v)); }
__device__ __forceinline__ void pin(float& v) { asm("" : "+v"(v)); }
// LDS-only barrier: does NOT drain vmcnt (x prefetch stays in flight).
__device__ __forceinline__ void bar_lds() {
    asm volatile("s_waitcnt lgkmcnt(0)\n\ts_barrier" ::: "memory");
}

// fold 8 accs over 16 kt-lanes, XOR-permuted: lane ends with the full sum
// of virtual slot p(kt) = ((kt&1)<<2)|(kt&2)|((kt>>2)&1).
__device__ __forceinline__ float fold16x8(const float a[8]) {
    float b0 = a[0] + dpp_movf<0xB1>(a[4]);   // xor1 (quad_perm [1,0,3,2])
    float b1 = a[1] + dpp_movf<0xB1>(a[5]);
    float b2 = a[2] + dpp_movf<0xB1>(a[6]);
    float b3 = a[3] + dpp_movf<0xB1>(a[7]);
    float c0 = b0 + dpp_movf<0x4E>(b2);       // xor2 (quad_perm [2,3,0,1])
    float c1 = b1 + dpp_movf<0x4E>(b3);
    float d  = c0 + swz_xor4(c1);             // xor4 (only DS hop)
    return d + dpp_movf<0x128>(d);            // xor8 (row_ror:8)
}
// fold 4 accs over 16 kt-lanes: lane ends with full sum of slot
// p2(kt) = (kt&2)|((kt>>2)&1).
__device__ __forceinline__ float fold16x4(const float a[4]) {
    float b0 = a[0] + dpp_movf<0xB1>(a[0]);
    float b1 = a[1] + dpp_movf<0xB1>(a[1]);
    float b2 = a[2] + dpp_movf<0xB1>(a[2]);
    float b3 = a[3] + dpp_movf<0xB1>(a[3]);
    float c0 = b0 + dpp_movf<0x4E>(b2);
    float c1 = b1 + dpp_movf<0x4E>(b3);
    float d  = c0 + swz_xor4(c1);
    return d + dpp_movf<0x128>(d);
}

__global__ __launch_bounds__(512, 2)
void gru_fused(const float* __restrict__ x,     // [B,T,I]
               const float* __restrict__ W_ih,  // [3H,I]
               const float* __restrict__ W_hh,  // [3H,H]
               const float* __restrict__ b_ih,  // [3H]
               const float* __restrict__ b_hh,  // [3H]
               float* __restrict__ out)         // [B,H]
{
    const int b   = blockIdx.x;
    const int tid = threadIdx.x;
    const int wid = tid >> 6;
    const int l   = tid & 63;
    const int kt  = l & 15;
    const int kb  = kt * 8;
    const int p   = ((kt & 1) << 2) | (kt & 2) | ((kt >> 2) & 1);
    const int p2  = (kt & 2) | ((kt >> 2) & 1);
    const int jbase = wid * 16 + ((l >> 4) << 2);

    __shared__ __align__(16) float h_db[2][16][12];  // double-buffered h

    const float L2E = 1.4426950408889634f;   // log2(e)
    const float K2  = 2.0f * L2E;

    // ---- recurrent weights as k-pairs (v2f); r/z prescaled by log2e,
    //      n prescaled by 2*log2e; PINNED into VGPRs ----
    v2f wrz2[8][4];
    #pragma unroll
    for (int i = 0; i < 8; ++i) {
        const int u = i ^ p;
        const int g = (u >> 2) * Hh + jbase + (u & 3);
        const v2f* wp = reinterpret_cast<const v2f*>(W_hh + (size_t)g * Hh + kb);
        #pragma unroll
        for (int kk = 0; kk < 4; ++kk) {
            v2f w = wp[kk];
            w[0] *= L2E; w[1] *= L2E;
            wrz2[i][kk] = w;
            pin(wrz2[i][kk]);
        }
    }
    v2f wn2[4][4];
    #pragma unroll
    for (int q = 0; q < 4; ++q) {
        const int g = 2 * Hh + jbase + (q ^ p2);
        const v2f* wp = reinterpret_cast<const v2f*>(W_hh + (size_t)g * Hh + kb);
        #pragma unroll
        for (int kk = 0; kk < 4; ++kk) {
            v2f w = wp[kk];
            w[0] *= K2; w[1] *= K2;
            wn2[q][kk] = w;
            pin(wn2[q][kk]);
        }
    }

    // ---- x-side weights: lane kt covers x idx xi0 (+1 if kt<7) ----
    const int xi0  = (kt < 7) ? kt * 2 : 7 + kt;      // 0..13 / 14..22
    const int xoff = (kt < 7) ? 1 : 0;                // dup-load if 0 (w=0)
    v2f wx2[8];
    #pragma unroll
    for (int i = 0; i < 8; ++i) {
        const int u = i ^ p;
        const int g = (u >> 2) * Hh + jbase + (u & 3);
        wx2[i][0] = W_ih[(size_t)g * Ii + xi0] * L2E;
        wx2[i][1] = xoff ? W_ih[(size_t)g * Ii + xi0 + 1] * L2E : 0.0f;
        pin(wx2[i]);
    }
    v2f wxn2[4];
    #pragma unroll
    for (int q = 0; q < 4; ++q) {
        const int g = 2 * Hh + jbase + (q ^ p2);
        wxn2[q][0] = W_ih[(size_t)g * Ii + xi0] * K2;
        wxn2[q][1] = xoff ? W_ih[(size_t)g * Ii + xi0 + 1] * K2 : 0.0f;
        pin(wxn2[q]);
    }

    // ---- per-lane biases (post-fold), prescaled, pinned ----
    const int gp = (p >> 2) * Hh + jbase + (p & 3);
    float brz_l = (b_ih[gp] + b_hh[gp]) * L2E;
    const int jn = jbase + p2;
    float bhn_l = b_hh[2 * Hh + jn] * K2;
    float bxn_l = b_ih[2 * Hh + jn] * K2;
    pin(brz_l); pin(bhn_l); pin(bxn_l);

    const float* xrow = x + (size_t)b * Tt * Ii;

    // ---- init ----
    if (tid < Hh) h_db[0][tid >> 3][tid & 7] = 0.0f;
    // depth-2 x prefetch: P0 serves even steps, P1 odd steps.
    float x0a = xrow[xi0],      x0b = xrow[xi0 + xoff];
    float x1a = xrow[Ii + xi0], x1b = xrow[Ii + xi0 + xoff];
    int xob = 2 * Ii + xi0;                 // element index of row step+2
    float h_reg = 0.0f, acc_mean = 0.0f;
    const bool writer = ((kt & 9) == 0);    // kt in {0,2,4,6} -> p in {0,2,1,3}
    const int  jw = jbase + p;
    bar_lds();

    auto body = [&](auto CUR, int s) {
        constexpr int cur = decltype(CUR)::v;
        const int step = s + cur;

        // ---- h tile: 8 floats as 2x b128, split into pairs ----
        const v4f hA = *reinterpret_cast<const v4f*>(&h_db[cur][kt][0]);
        const v4f hB = *reinterpret_cast<const v4f*>(&h_db[cur][kt][4]);
        v2f hp[4];
        hp[0] = __builtin_shufflevector(hA, hA, 0, 1);
        hp[1] = __builtin_shufflevector(hA, hA, 2, 3);
        hp[2] = __builtin_shufflevector(hB, hB, 0, 1);
        hp[3] = __builtin_shufflevector(hB, hB, 2, 3);

        // ---- packed recurrent MACs: 8 r/z + 4 n gates ----
        v2f acc[8], accn[4];
        #pragma unroll
        for (int i = 0; i < 8; ++i) acc[i] = pk_mul(wrz2[i][0], hp[0]);
        #pragma unroll
        for (int q = 0; q < 4; ++q) accn[q] = pk_mul(wn2[q][0], hp[0]);
        #pragma unroll
        for (int kk = 1; kk < 4; ++kk) {
            #pragma unroll
            for (int i = 0; i < 8; ++i) pk_fma(acc[i], wrz2[i][kk], hp[kk]);
            #pragma unroll
            for (int q = 0; q < 4; ++q) pk_fma(accn[q], wn2[q][kk], hp[kk]);
        }

        // ---- x-side: r/z folds into acc; n kept separate ----
        v2f xpv;
        if constexpr (cur == 0) { xpv[0] = x0a; xpv[1] = x0b; }
        else                    { xpv[0] = x1a; xpv[1] = x1b; }
        #pragma unroll
        for (int i = 0; i < 8; ++i) pk_fma(acc[i], wx2[i], xpv);
        float arz[8];
        #pragma unroll
        for (int i = 0; i < 8; ++i) arz[i] = acc[i][0] + acc[i][1];
        float an[4], axn[4];
        #pragma unroll
        for (int q = 0; q < 4; ++q) {
            an[q] = accn[q][0] + accn[q][1];
            v2f tq = pk_mul(wxn2[q], xpv);
            axn[q] = tq[0] + tq[1];
        }

        // ---- reload this parity's x pair for step+2 (vmcnt wait lands
        //      ~2 steps downstream; barrier does not drain it) ----
        if constexpr (cur == 0) { x0a = xrow[xob]; x0b = xrow[xob + xoff]; }
        else                    { x1a = xrow[xob]; x1b = xrow[xob + xoff]; }
        if (step + 3 < Tt) xob += Ii;

        // ---- folds (all in-wave) + biases ----
        const float rz_tot = fold16x8(arz) + brz_l;   // r/z pre-act at slot p
        const float ghn = fold16x4(an) + bhn_l;       // rec n-sum at slot p2
        const float gxn = fold16x4(axn) + bxn_l;      // x-side n-sum at slot p2

        // ---- in-register epilogue (valid on even-kt lanes) ----
        const float zin = dpp_movf<0xB1>(rz_tot);     // neighbor's z pre-act
        const float r  = __builtin_amdgcn_rcpf(1.0f + fexp2(-rz_tot));
        const float z  = __builtin_amdgcn_rcpf(1.0f + fexp2(-zin));
        const float npre = fmaf(r, ghn, gxn);         // pre-scaled by 2log2e
        const float tt2  = __builtin_amdgcn_rcpf(1.0f + fexp2(-npre));
        const float nn   = fmaf(2.0f, tt2, -1.0f);    // tanh
        const float h_new = fmaf(z, h_reg - nn, nn);
        h_reg = h_new;
        if (writer) {
            acc_mean += h_new;
            h_db[cur ^ 1][jw >> 3][jw & 7] = h_new;
        }
        bar_lds();   // LDS-only barrier, once per step
    };

    for (int s = 0; s < Tt; s += 2) {
        body(ic<0>{}, s);
        body(ic<1>{}, s);
    }

    if (writer) out[(size_t)b * Hh + jw] = acc_mean * (1.0f / Tt);
}

extern "C" void kernel_launch(void* const* d_in, const int* in_sizes, int n_in,
                              void* d_out, int out_size, void* d_ws, size_t ws_size,
                              hipStream_t stream) {
    const float* x    = (const float*)d_in[0];
    const float* W_ih = (const float*)d_in[1];
    const float* W_hh = (const float*)d_in[2];
    const float* b_ih = (const float*)d_in[3];
    const float* b_hh = (const float*)d_in[4];
    float* out = (float*)d_out;

    gru_fused<<<Bb, 512, 0, stream>>>(x, W_ih, W_hh, b_ih, b_hh, out);
}